// Round 2
// baseline (84.490 us; speedup 1.0000x reference)
//
#include <hip/hip_runtime.h>
#include <cstdint>

namespace {

constexpr int NB = 320;   // batch
constexpr int ND = 128;   // feature dim
constexpr int NC = 80;    // label dim
constexpr int NANCH = 30;

// ---- workspace layout (byte offsets) ----
constexpr size_t OFF_FD   = 0;          // float[320*320] = 409600 B
constexpr size_t OFF_PACK = 409600;     // u64[640]
constexpr size_t OFF_CNT  = 414720;     // float[320] label popcount
constexpr size_t OFF_DIV  = 416000;     // float[320]
constexpr size_t OFF_CTR  = 417280;     // u32 arrival counter

__global__ __launch_bounds__(256) void k_fused(
    const int* __restrict__ label,
    const float* __restrict__ src,
    const float* __restrict__ tgt,
    float* __restrict__ fd,
    unsigned long long* __restrict__ packed,
    float* __restrict__ cnt,
    float* __restrict__ divr,
    unsigned int* __restrict__ ctr,
    float* __restrict__ out)
{
    const int a = blockIdx.x;
    const int tid = threadIdx.x;
    const int w = tid >> 6, lane = tid & 63;

    __shared__ float sa[ND];
    __shared__ float snsa;
    __shared__ float red[256];

    // ---- phase 1: per-row prep + fd row + diversity ----
    if (tid < ND) sa[tid] = src[a * ND + tid];
    if (w == 0) {
        float s0 = src[a * ND + lane];
        float s1 = src[a * ND + lane + 64];
        float v = s0 * s0 + s1 * s1;
        for (int off = 32; off > 0; off >>= 1) v += __shfl_down(v, off);
        if (lane == 0) snsa = sqrtf(v);
    } else if (w == 1) {
        int l0 = label[a * NC + lane];                          // c 0..63
        int l1 = (lane < NC - 64) ? label[a * NC + 64 + lane] : 0; // c 64..79
        unsigned long long b0 = __ballot(l0 != 0);
        unsigned long long b1 = __ballot(l1 != 0);
        if (lane == 0) {
            packed[2 * a] = b0;
            packed[2 * a + 1] = b1;
            cnt[a] = (float)(__popcll(b0) + __popcll(b1));
        }
    }
    __syncthreads();

    const float nsa = snsa;
    float acc = 0.f;
    for (int j = tid; j < NB; j += 256) {
        const float4* tp = reinterpret_cast<const float4*>(tgt + j * ND);
        float dot = 0.f, tn = 0.f;
#pragma unroll
        for (int d = 0; d < ND / 4; ++d) {
            float4 t = tp[d];
            dot += sa[4 * d + 0] * t.x + sa[4 * d + 1] * t.y +
                   sa[4 * d + 2] * t.z + sa[4 * d + 3] * t.w;
            tn += t.x * t.x + t.y * t.y + t.z * t.z + t.w * t.w;
        }
        float sim = dot / fmaxf(nsa * sqrtf(tn), 1e-8f);
        float f = fmaxf(1.0f - sim, 0.0f);
        fd[a * NB + j] = f;
        acc += f;
    }
    red[tid] = acc;
    __syncthreads();
    for (int st = 128; st > 0; st >>= 1) {
        if (tid < st) red[tid] += red[tid + st];
        __syncthreads();
    }
    if (tid == 0) divr[a] = red[0] / (float)NB;

    // ---- arrival: last block proceeds to phase 2 ----
    __threadfence();                       // release: publish fd/divr/packed/cnt
    __shared__ int isLast;
    if (tid == 0) isLast = (atomicAdd(ctr, 1u) == (unsigned)(gridDim.x - 1));
    __syncthreads();
    if (!isLast) return;
    __threadfence();                       // acquire: see all blocks' writes

    // ---- phase 2a: top-30 diversity (wave 0, ties -> lowest index) ----
    __shared__ float dv[NB];
    __shared__ int alist[NANCH];
    for (int j = tid; j < NB; j += 256) dv[j] = divr[j];
    __syncthreads();
    if (w == 0) {
        volatile float* dvv = dv;          // wave-internal LDS ordering
        for (int r = 0; r < NANCH; ++r) {
            float bv = -1e30f; int bi = NB;
#pragma unroll
            for (int t = 0; t < 5; ++t) {
                int idx = lane + 64 * t;
                float v = dvv[idx];
                if (v > bv) { bv = v; bi = idx; }
            }
            for (int off = 32; off > 0; off >>= 1) {
                float ov = __shfl_xor(bv, off);
                int oi = __shfl_xor(bi, off);
                if (ov > bv || (ov == bv && oi < bi)) { bv = ov; bi = oi; }
            }
            if (lane == 0) { dvv[bi] = -1e30f; alist[r] = bi; }
        }
    }
    __syncthreads();

    // ---- phase 2b: anchors distributed across 4 waves; deterministic ----
    __shared__ float fdw[4][NB];
    __shared__ unsigned short plw[4][NB], nlw[4][NB];
    __shared__ double sred[256];
    __shared__ long long cw[4];

    double s_acc = 0.0;
    long long c_acc = 0;
    for (int r = w; r < NANCH; r += 4) {
        const int a2 = alist[r];
        for (int j = lane; j < NB; j += 64) fdw[w][j] = fd[a2 * NB + j];
        const unsigned long long a0 = packed[2 * a2], a1 = packed[2 * a2 + 1];
        const float sna = sqrtf(cnt[a2]);
        int pbase = 0, nbase = 0;
#pragma unroll
        for (int c = 0; c < 5; ++c) {
            int j = c * 64 + lane;
            unsigned long long c0 = packed[2 * j], c1 = packed[2 * j + 1];
            float dotf = (float)(__popcll(a0 & c0) + __popcll(a1 & c1));
            float ld = 1.0f - fminf(1.0f, dotf / (sna * sqrtf(cnt[j])));
            bool pf = (j != a2) && (ld <= 0.2f);
            bool nf = (j != a2) && (ld >= 0.5f);
            unsigned long long pb = __ballot(pf);
            unsigned long long nb = __ballot(nf);
            unsigned long long lm = (1ull << lane) - 1ull;
            if (pf) plw[w][pbase + __popcll(pb & lm)] = (unsigned short)j;
            if (nf) nlw[w][nbase + __popcll(nb & lm)] = (unsigned short)j;
            pbase += __popcll(pb);
            nbase += __popcll(nb);
        }
        const int total = pbase * nbase;   // pos/neg disjoint => p != n automatic
        for (int idx = lane; idx < total; idx += 64) {
            int p = plw[w][idx / nbase];
            int n = nlw[w][idx % nbase];
            float v = fdw[w][p] - fdw[w][n] + 0.5f;
            if (v > 0.f) s_acc += (double)v;
        }
        if (lane == 0) c_acc += total;
    }
    sred[tid] = s_acc;
    if (lane == 0) cw[w] = c_acc;
    __syncthreads();
    for (int st = 128; st > 0; st >>= 1) {
        if (tid < st) sred[tid] += sred[tid + st];
        __syncthreads();
    }
    if (tid == 0) {
        double C = (double)(cw[0] + cw[1] + cw[2] + cw[3]);
        out[0] = (float)(sred[0] / (C + 1e-4));
    }
}

} // namespace

extern "C" void kernel_launch(void* const* d_in, const int* in_sizes, int n_in,
                              void* d_out, int out_size, void* d_ws, size_t ws_size,
                              hipStream_t stream) {
    const int* label = (const int*)d_in[0];
    const float* src = (const float*)d_in[1];
    const float* tgt = (const float*)d_in[2];

    char* ws = (char*)d_ws;
    float* fd = (float*)(ws + OFF_FD);
    unsigned long long* packed = (unsigned long long*)(ws + OFF_PACK);
    float* cnt = (float*)(ws + OFF_CNT);
    float* divr = (float*)(ws + OFF_DIV);
    unsigned int* ctr = (unsigned int*)(ws + OFF_CTR);

    hipMemsetAsync(ctr, 0, sizeof(unsigned int), stream);  // graph-capturable
    k_fused<<<NB, 256, 0, stream>>>(label, src, tgt, fd, packed, cnt, divr, ctr,
                                    (float*)d_out);
}

// Round 3
// 58.008 us; speedup vs baseline: 1.4565x; 1.4565x over previous
//
#include <hip/hip_runtime.h>
#include <cstdint>

namespace {

constexpr int NB = 320;   // batch
constexpr int ND = 128;   // feature dim
constexpr int NC = 80;    // label dim
constexpr int NANCH = 30;

// ---- workspace layout (byte offsets) ----
constexpr size_t OFF_FD   = 0;          // float[320*320] = 409600 B
constexpr size_t OFF_PACK = 409600;     // u64[640]
constexpr size_t OFF_CNT  = 414720;     // float[320] label popcount
constexpr size_t OFF_DIV  = 416000;     // float[320]

// K1: per-row prep (src norm, label pack) + fd row + diversity mean.
__global__ __launch_bounds__(256) void k_fd(
    const int* __restrict__ label,
    const float* __restrict__ src,
    const float* __restrict__ tgt,
    float* __restrict__ fd,
    unsigned long long* __restrict__ packed,
    float* __restrict__ cnt,
    float* __restrict__ divr)
{
    const int a = blockIdx.x;
    const int tid = threadIdx.x;
    const int w = tid >> 6, lane = tid & 63;

    __shared__ float sa[ND];
    __shared__ float snsa;
    __shared__ float red[256];

    if (tid < ND) sa[tid] = src[a * ND + tid];
    if (w == 0) {
        float s0 = src[a * ND + lane];
        float s1 = src[a * ND + lane + 64];
        float v = s0 * s0 + s1 * s1;
        for (int off = 32; off > 0; off >>= 1) v += __shfl_down(v, off);
        if (lane == 0) snsa = sqrtf(v);
    } else if (w == 1) {
        int l0 = label[a * NC + lane];                              // c 0..63
        int l1 = (lane < NC - 64) ? label[a * NC + 64 + lane] : 0;  // c 64..79
        unsigned long long b0 = __ballot(l0 != 0);
        unsigned long long b1 = __ballot(l1 != 0);
        if (lane == 0) {
            packed[2 * a] = b0;
            packed[2 * a + 1] = b1;
            cnt[a] = (float)(__popcll(b0) + __popcll(b1));
        }
    }
    __syncthreads();

    const float nsa = snsa;
    float acc = 0.f;
    for (int j = tid; j < NB; j += 256) {
        const float4* tp = reinterpret_cast<const float4*>(tgt + j * ND);
        float dot = 0.f, tn = 0.f;
#pragma unroll
        for (int d = 0; d < ND / 4; ++d) {
            float4 t = tp[d];
            dot += sa[4 * d + 0] * t.x + sa[4 * d + 1] * t.y +
                   sa[4 * d + 2] * t.z + sa[4 * d + 3] * t.w;
            tn += t.x * t.x + t.y * t.y + t.z * t.z + t.w * t.w;
        }
        float sim = dot / fmaxf(nsa * sqrtf(tn), 1e-8f);
        float f = fmaxf(1.0f - sim, 0.0f);
        fd[a * NB + j] = f;
        acc += f;
    }
    red[tid] = acc;
    __syncthreads();
    for (int st = 128; st > 0; st >>= 1) {
        if (tid < st) red[tid] += red[tid + st];
        __syncthreads();
    }
    if (tid == 0) divr[a] = red[0] / (float)NB;
}

// K2: single block -- top-30 anchors, pos/neg classification, triplet sum.
__global__ __launch_bounds__(256) void k_tail(
    const unsigned long long* __restrict__ packed,
    const float* __restrict__ cnt,
    const float* __restrict__ fd,
    const float* __restrict__ divr,
    float* __restrict__ out)
{
    const int tid = threadIdx.x;
    const int w = tid >> 6, lane = tid & 63;

    __shared__ float dv[NB];
    __shared__ float snl[NB];                 // sqrt(label popcount)
    __shared__ unsigned long long pk[2 * NB];
    __shared__ int alist[NANCH];
    __shared__ float fdw[4][NB];
    __shared__ unsigned short plw[4][NB], nlw[4][NB];
    __shared__ double sred[256];
    __shared__ long long cw[4];

    for (int j = tid; j < NB; j += 256) {
        dv[j] = divr[j];
        snl[j] = sqrtf(cnt[j]);
    }
    for (int j = tid; j < 2 * NB; j += 256) pk[j] = packed[j];
    __syncthreads();

    // top-30 by diversity, ties -> lowest index (matches lax.top_k)
    if (w == 0) {
        volatile float* dvv = dv;
        for (int r = 0; r < NANCH; ++r) {
            float bv = -1e30f; int bi = NB;
#pragma unroll
            for (int t = 0; t < 5; ++t) {
                int idx = lane + 64 * t;
                float v = dvv[idx];
                if (v > bv) { bv = v; bi = idx; }
            }
            for (int off = 32; off > 0; off >>= 1) {
                float ov = __shfl_xor(bv, off);
                int oi = __shfl_xor(bi, off);
                if (ov > bv || (ov == bv && oi < bi)) { bv = ov; bi = oi; }
            }
            if (lane == 0) { dvv[bi] = -1e30f; alist[r] = bi; }
        }
    }
    __syncthreads();

    // anchors distributed across 4 waves; deterministic ballot compaction
    double s_acc = 0.0;
    long long c_acc = 0;
    for (int r = w; r < NANCH; r += 4) {
        const int a2 = alist[r];
        for (int j = lane; j < NB; j += 64) fdw[w][j] = fd[a2 * NB + j];
        const unsigned long long a0 = pk[2 * a2], a1 = pk[2 * a2 + 1];
        const float sna = snl[a2];
        int pbase = 0, nbase = 0;
#pragma unroll
        for (int c = 0; c < 5; ++c) {
            int j = c * 64 + lane;
            unsigned long long c0 = pk[2 * j], c1 = pk[2 * j + 1];
            float dotf = (float)(__popcll(a0 & c0) + __popcll(a1 & c1));
            float denom = sna * snl[j];
            bool valid = (j != a2) && (denom > 0.f);   // zero-label row -> NaN in ref -> excluded
            float ld = 1.0f - fminf(1.0f, dotf / denom);
            bool pf = valid && (ld <= 0.2f);
            bool nf = valid && (ld >= 0.5f);
            unsigned long long pb = __ballot(pf);
            unsigned long long nb = __ballot(nf);
            unsigned long long lm = (1ull << lane) - 1ull;
            if (pf) plw[w][pbase + __popcll(pb & lm)] = (unsigned short)j;
            if (nf) nlw[w][nbase + __popcll(nb & lm)] = (unsigned short)j;
            pbase += __popcll(pb);
            nbase += __popcll(nb);
        }
        // pos/neg disjoint (gamma < beta) => p != n automatic
        for (int pi = 0; pi < pbase; ++pi) {
            const float fp = fdw[w][plw[w][pi]];
            for (int ni = lane; ni < nbase; ni += 64) {
                float v = fp - fdw[w][nlw[w][ni]] + 0.5f;
                if (v > 0.f) s_acc += (double)v;
            }
        }
        if (lane == 0) c_acc += (long long)pbase * nbase;
    }
    sred[tid] = s_acc;
    if (lane == 0) cw[w] = c_acc;
    __syncthreads();
    for (int st = 128; st > 0; st >>= 1) {
        if (tid < st) sred[tid] += sred[tid + st];
        __syncthreads();
    }
    if (tid == 0) {
        double C = (double)(cw[0] + cw[1] + cw[2] + cw[3]);
        out[0] = (float)(sred[0] / (C + 1e-4));
    }
}

} // namespace

extern "C" void kernel_launch(void* const* d_in, const int* in_sizes, int n_in,
                              void* d_out, int out_size, void* d_ws, size_t ws_size,
                              hipStream_t stream) {
    const int* label = (const int*)d_in[0];
    const float* src = (const float*)d_in[1];
    const float* tgt = (const float*)d_in[2];

    char* ws = (char*)d_ws;
    float* fd = (float*)(ws + OFF_FD);
    unsigned long long* packed = (unsigned long long*)(ws + OFF_PACK);
    float* cnt = (float*)(ws + OFF_CNT);
    float* divr = (float*)(ws + OFF_DIV);

    k_fd  <<<NB, 256, 0, stream>>>(label, src, tgt, fd, packed, cnt, divr);
    k_tail<<<1, 256, 0, stream>>>(packed, cnt, fd, divr, (float*)d_out);
}